// Round 4
// baseline (40.348 us; speedup 1.0000x reference)
//
#include <hip/hip_runtime.h>
#include <hip/hip_bf16.h>

// Problem constants (from reference)
#define B_   32
#define N_   64
#define C_   3
#define H_   512
#define W_   512
#define P_   16
#define PLANE (H_ * W_)          // 262144 floats per channel plane
#define IMG   (C_ * PLANE)       // 786432 floats per batch image

typedef float f32x4 __attribute__((ext_vector_type(4)));   // native vector for nontemporal builtins

// One block = TWO output rows (b, r0) and (b, r0+1), all 3 channels.
// 256 threads: tid>>7 selects the row, (tid&127)*4 the float4 column.
// Waves 0 and 1 each build the overlap list for one row (ballot+compact in
// LDS, expected length ~2), then all threads stream image->out with the
// patch values added in registers. Pure gather: no atomics, one dispatch.
__global__ __launch_bounds__(256)
void ImagePatch_fused_kernel(const float* __restrict__ image,
                             const float* __restrict__ emb,
                             const int*   __restrict__ labels,
                             const int*   __restrict__ top_left,
                             float*       __restrict__ out) {
    __shared__ int s_cnt[2];
    __shared__ int s_dr[2][N_];   // r - tr  in [0,16)
    __shared__ int s_tc[2][N_];   // patch left col
    __shared__ int s_lb[2][N_];   // label

    const int bid = blockIdx.x;
    const int r0  = (bid & (H_ / 2 - 1)) * 2;   // first row of the pair
    const int b   = bid >> 8;                   // / (H_/2)
    const int tid = threadIdx.x;

    // ---- build overlap lists: wave 0 -> row r0, wave 1 -> row r0+1 ----
    if (tid < 128) {
        const int w    = tid >> 6;              // which row of the pair
        const int lane = tid & 63;
        const int idx  = b * N_ + lane;
        const int tr   = top_left[idx * 2];
        const unsigned dr = (unsigned)(r0 + w - tr);
        const bool cover  = dr < P_;
        const unsigned long long m = __ballot(cover);
        if (cover) {
            const int pos = __popcll(m & ((1ull << lane) - 1ull));
            s_dr[w][pos] = (int)dr;
            s_tc[w][pos] = top_left[idx * 2 + 1];
            s_lb[w][pos] = labels[idx];
        }
        if (lane == 0) s_cnt[w] = __popcll(m);
    }
    __syncthreads();

    // ---- streaming copy + gather-add ----
    const int w  = tid >> 7;                    // row select
    const int c0 = (tid & 127) * 4;
    const size_t base = (size_t)b * IMG + (size_t)(r0 + w) * W_ + c0;

    f32x4 v0 = __builtin_nontemporal_load((const f32x4*)(image + base));
    f32x4 v1 = __builtin_nontemporal_load((const f32x4*)(image + base + PLANE));
    f32x4 v2 = __builtin_nontemporal_load((const f32x4*)(image + base + 2 * PLANE));

    const int cnt = s_cnt[w];
    for (int k = 0; k < cnt; ++k) {
        const int tc = s_tc[w][k];
        if (c0 + 3 >= tc && c0 < tc + P_) {     // [c0,c0+4) ∩ [tc,tc+16) ?
            const float* e = emb + s_lb[w][k] * (C_ * P_ * P_) + s_dr[w][k] * P_;
            #pragma unroll
            for (int q = 0; q < 4; ++q) {
                const unsigned dc = (unsigned)(c0 + q - tc);
                if (dc < P_) {
                    v0[q] += e[dc];                 // ch 0
                    v1[q] += e[P_ * P_ + dc];       // ch 1
                    v2[q] += e[2 * P_ * P_ + dc];   // ch 2
                }
            }
        }
    }

    __builtin_nontemporal_store(v0, (f32x4*)(out + base));
    __builtin_nontemporal_store(v1, (f32x4*)(out + base + PLANE));
    __builtin_nontemporal_store(v2, (f32x4*)(out + base + 2 * PLANE));
}

extern "C" void kernel_launch(void* const* d_in, const int* in_sizes, int n_in,
                              void* d_out, int out_size, void* d_ws, size_t ws_size,
                              hipStream_t stream) {
    const float* image    = (const float*)d_in[0];   // [B, 3, H, W]
    const float* emb      = (const float*)d_in[1];   // [128, 768]
    const int*   labels   = (const int*)d_in[2];     // [B, N]
    const int*   top_left = (const int*)d_in[3];     // [B, N, 2]
    float*       out      = (float*)d_out;           // [B, 3, H, W]

    const int grid = B_ * H_ / 2;                    // 8192 blocks, 2 rows each
    ImagePatch_fused_kernel<<<grid, 256, 0, stream>>>(image, emb, labels, top_left, out);
}